// Round 8
// baseline (462.625 us; speedup 1.0000x reference)
//
#include <hip/hip_runtime.h>
#include <hip/hip_fp16.h>

#define N_NODES 100000
#define N_EDGES 1600000
#define DIM 128
#define NC 40

#define BUCKET_SHIFT 7
#define BUCKET_NODES 128
#define NBUCKET ((N_NODES + BUCKET_NODES - 1) / BUCKET_NODES)   // 782
#define NBIN 1024                                               // padded bins for scan
#define EPB 4096                                                // edges per binfill block
#define NBLK_FILL ((N_EDGES + EPB - 1) / EPB)                   // 391

typedef _Float16 f16x8 __attribute__((ext_vector_type(8)));
typedef float f32x4 __attribute__((ext_vector_type(4)));

// ---------------- CSR hist + x -> fp16 convert + zero-row init (fused) ----------------
__global__ __launch_bounds__(256) void k_hist_cvt(const int2* __restrict__ ei, int* __restrict__ deg,
                                                  const float* __restrict__ x, __half* __restrict__ xh,
                                                  __half* __restrict__ y) {
    int i = blockIdx.x * 256 + threadIdx.x;       // 6250*256 == N_EDGES exactly
    if (blockIdx.x == 0) {
        // zero rows at index N_NODES (targets of branchless invalid-lane gathers)
        if (threadIdx.x < 16) ((uint4*)xh)[(size_t)N_NODES * (DIM / 8) + threadIdx.x] = (uint4){0, 0, 0, 0};
        else if (threadIdx.x < 21) ((uint4*)y)[(size_t)N_NODES * 5 + threadIdx.x - 16] = (uint4){0, 0, 0, 0};
    }
    int2 e = ei[i];
    atomicAdd(&deg[e.y + 1], 1);
    // convert 8 floats -> 8 halves; 6250*256*8 == N_NODES*DIM exactly
    float4 v0 = ((const float4*)x)[(size_t)i * 2];
    float4 v1 = ((const float4*)x)[(size_t)i * 2 + 1];
    __half2 h01 = __float22half2_rn(make_float2(v0.x, v0.y));
    __half2 h23 = __float22half2_rn(make_float2(v0.z, v0.w));
    __half2 h45 = __float22half2_rn(make_float2(v1.x, v1.y));
    __half2 h67 = __float22half2_rn(make_float2(v1.z, v1.w));
    uint4 o;
    o.x = *(unsigned*)&h01; o.y = *(unsigned*)&h23;
    o.z = *(unsigned*)&h45; o.w = *(unsigned*)&h67;
    ((uint4*)xh)[i] = o;
}

#define SCAN_N (N_NODES + 1)
#define SCAN_T 256
#define SCAN_PER 32
#define SCAN_CHUNK (SCAN_T * SCAN_PER)                      // 8192
#define SCAN_NB ((SCAN_N + SCAN_CHUNK - 1) / SCAN_CHUNK)    // 13

__global__ __launch_bounds__(SCAN_T) void k_scan1(int* __restrict__ a, int* __restrict__ bsums) {
    __shared__ int wtot[SCAN_T / 64];
    int t = threadIdx.x, lane = t & 63, wid = t >> 6;
    int base = blockIdx.x * SCAN_CHUNK + t * SCAN_PER;
    int v[SCAN_PER];
    int run = 0;
    #pragma unroll
    for (int j = 0; j < SCAN_PER; ++j) {
        int idx = base + j;
        int x = (idx < SCAN_N) ? a[idx] : 0;
        run += x;
        v[j] = run;
    }
    int incl = run;
    #pragma unroll
    for (int d = 1; d < 64; d <<= 1) {
        int u = __shfl_up(incl, d, 64);
        if (lane >= d) incl += u;
    }
    if (lane == 63) wtot[wid] = incl;
    __syncthreads();
    int add = incl - run;
    for (int w = 0; w < wid; ++w) add += wtot[w];
    #pragma unroll
    for (int j = 0; j < SCAN_PER; ++j) {
        int idx = base + j;
        if (idx < SCAN_N) a[idx] = v[j] + add;
    }
    if (t == 0) {
        int tot = 0;
        for (int w = 0; w < SCAN_T / 64; ++w) tot += wtot[w];
        bsums[blockIdx.x] = tot;
    }
}

// scan2 finalizes row_ptr and mirrors bucket bases into bcur (binfill's global cursors)
__global__ __launch_bounds__(SCAN_T) void k_scan2(int* __restrict__ a, const int* __restrict__ bsums,
                                                  int* __restrict__ bcur) {
    int off = 0;
    for (int i = 0; i < (int)blockIdx.x; ++i) off += bsums[i];
    int base = blockIdx.x * SCAN_CHUNK + threadIdx.x;
    #pragma unroll
    for (int j = 0; j < SCAN_PER; ++j) {
        int idx = base + j * SCAN_T;
        if (idx < SCAN_N) {
            int v = a[idx] + off;
            a[idx] = v;
            if ((idx & (BUCKET_NODES - 1)) == 0 && idx < N_NODES) bcur[idx >> BUCKET_SHIFT] = v;
        }
    }
}

// ---------------- binfill: LDS counting-sort edges by 128-node bucket, coalesced staged writes ----
// staged entry: src | (dst_local << 17)  (src<2^17, dst_local<2^7)
__global__ __launch_bounds__(256) void k_binfill(const int2* __restrict__ ei, int* __restrict__ bcur,
                                                 int* __restrict__ stg) {
    __shared__ int hist[NBIN];
    __shared__ int offs[NBIN];
    __shared__ int gbase[NBIN];
    __shared__ int cnt[NBIN];
    __shared__ int lds[EPB];
    __shared__ int wt[4];
    int t = threadIdx.x;
    int e0 = blockIdx.x * EPB;
    int bec = N_EDGES - e0; if (bec > EPB) bec = EPB;

    #pragma unroll
    for (int j = 0; j < NBIN / 256; ++j) { hist[t + j * 256] = 0; cnt[t + j * 256] = 0; }
    __syncthreads();

    // phase 1: histogram
    for (int k = 0; k < EPB / 256; ++k) {
        int i = e0 + t + k * 256;
        if (i < N_EDGES) {
            int2 e = ei[i];
            atomicAdd(&hist[e.y >> BUCKET_SHIFT], 1);
        }
    }
    __syncthreads();

    // phase 2: exclusive scan of hist[1024]
    int lane = t & 63, w = t >> 6;
    int h[4], p = 0;
    #pragma unroll
    for (int j = 0; j < 4; ++j) { h[j] = hist[t * 4 + j]; p += h[j]; }
    int inc = p;
    #pragma unroll
    for (int d = 1; d < 64; d <<= 1) {
        int u = __shfl_up(inc, d, 64);
        if (lane >= d) inc += u;
    }
    if (lane == 63) wt[w] = inc;
    __syncthreads();
    int add = inc - p;
    for (int k = 0; k < w; ++k) add += wt[k];
    int run = add;
    #pragma unroll
    for (int j = 0; j < 4; ++j) { offs[t * 4 + j] = run; run += h[j]; }
    __syncthreads();

    // phase 3: reserve global ranges (one atomic per non-empty bin)
    #pragma unroll
    for (int j = 0; j < 4; ++j) {
        int b = t * 4 + j;
        if (b < NBUCKET && h[j] > 0) gbase[b] = atomicAdd(&bcur[b], h[j]);
    }
    __syncthreads();

    // phase 4: scatter packed edges into LDS in bin order
    for (int k = 0; k < EPB / 256; ++k) {
        int i = e0 + t + k * 256;
        if (i < N_EDGES) {
            int2 e = ei[i];
            int b = e.y >> BUCKET_SHIFT;
            int pos = offs[b] + atomicAdd(&cnt[b], 1);
            lds[pos] = e.x | ((e.y & (BUCKET_NODES - 1)) << 17);
        }
    }
    __syncthreads();

    // phase 5: coalesced write-out (bin of position i via binary search on offs)
    for (int i = t; i < bec; i += 256) {
        int lo = 0, hi = NBIN - 1;
        while (lo < hi) { int mid = (lo + hi + 1) >> 1; if (offs[mid] <= i) lo = mid; else hi = mid - 1; }
        stg[gbase[lo] + (i - offs[lo])] = lds[i];
    }
}

// ---------------- per-bucket CSR fill: scatter confined to one block's 8KB window ----------------
__global__ __launch_bounds__(256) void k_csr_local(const int* __restrict__ row_ptr, const int* __restrict__ stg,
                                                   int* __restrict__ csr) {
    __shared__ int cur[BUCKET_NODES];
    int t = threadIdx.x, b = blockIdx.x;
    int n0 = b * BUCKET_NODES;
    int nn = N_NODES - n0; if (nn > BUCKET_NODES) nn = BUCKET_NODES;
    if (t < nn) cur[t] = row_ptr[n0 + t];
    __syncthreads();
    int beg = row_ptr[n0], end = row_ptr[n0 + nn];
    for (int i = beg + t; i < end; i += 256) {
        int e = stg[i];
        int dl = (e >> 17) & (BUCKET_NODES - 1);
        int pos = atomicAdd(&cur[dl], 1);
        csr[pos] = e & 0x1FFFF;
    }
}

// ---------------- pack W1a/W1b (128x128) and W2a (128x40->48) into fp16 MFMA B-frags ----------------
__global__ __launch_bounds__(256) void k_pack(const float* __restrict__ W1a, const float* __restrict__ W1b,
                                              const float* __restrict__ W2a,
                                              _Float16* __restrict__ Pa, _Float16* __restrict__ Pb,
                                              _Float16* __restrict__ Pc) {
    int bid = blockIdx.x, tid = threadIdx.x;
    if (bid < 16) {
        const float* W = (bid < 8) ? W1a : W1b;
        _Float16* P = (bid < 8) ? Pa : Pb;
        int t = (bid & 7) * 256 + tid;          // 0..2047
        int l = t & 63, nt = (t >> 6) & 7, kt = t >> 9;
        int n = nt * 16 + (l & 15);
        int kb = kt * 32 + (l >> 4) * 8;
        #pragma unroll
        for (int j = 0; j < 8; ++j)
            P[(size_t)t * 8 + j] = (_Float16)W[(size_t)(kb + j) * DIM + n];
    } else {
        int t = (bid - 16) * 256 + tid;         // 0..767
        if (t < 768) {
            int l = t & 63, u = t >> 6;          // u = kt*3 + nt
            int nt = u % 3, kt = u / 3;
            int n = nt * 16 + (l & 15);
            int kb = kt * 32 + (l >> 4) * 8;
            #pragma unroll
            for (int j = 0; j < 8; ++j) {
                float wv = (n < NC) ? W2a[(size_t)(kb + j) * NC + n] : 0.f;
                Pc[(size_t)t * 8 + j] = (_Float16)wv;
            }
        }
    }
}

// ---------------- layer 1 aggregation (branchless, zero-row padded): hp = x + segsum(x[src]) -------
__global__ __launch_bounds__(256) void k_gather1(const __half2* __restrict__ xh2, const int* __restrict__ row_ptr,
                                                 const int* __restrict__ csr_src, __half2* __restrict__ hp2) {
    int lane = threadIdx.x & 63, wid = threadIdx.x >> 6;
    int n = blockIdx.x * 4 + wid;
    float2 acc = __half22float2(xh2[(size_t)n * 64 + lane]);
    int i0 = row_ptr[n], e = row_ptr[n + 1];
    int niter = (e - i0 + 7) >> 3;
    for (int k = 0; k < niter; ++k) {
        int base = i0 + k * 8;
        int s[8];
        #pragma unroll
        for (int u = 0; u < 8; ++u) {
            int idx = base + u;
            s[u] = (idx < e) ? csr_src[idx] : N_NODES;   // N_NODES = zero row
        }
        float2 v[8];
        #pragma unroll
        for (int u = 0; u < 8; ++u) v[u] = __half22float2(xh2[(size_t)s[u] * 64 + lane]);
        #pragma unroll
        for (int u = 0; u < 8; ++u) { acc.x += v[u].x; acc.y += v[u].y; }
    }
    hp2[(size_t)n * 64 + lane] = __float22half2_rn(acc);
}

// ---------------- fused MLP via fp16 MFMA: y = relu(relu(hp@W1a+b1a)@W1b+b1b) @ W2a ----------------
__global__ __launch_bounds__(256) void k_mlp(const __half* __restrict__ hp,
    const _Float16* __restrict__ Pa, const _Float16* __restrict__ Pb, const _Float16* __restrict__ Pc,
    const float* __restrict__ b1a, const float* __restrict__ b1b, __half* __restrict__ y) {
    __shared__ _Float16 A[64][136];   // +8 pad (16B): aligned frag reads
    __shared__ _Float16 H[64][136];
    int t = threadIdx.x;
    size_t row0 = (size_t)blockIdx.x * 64;

    for (int i = t; i < 1024; i += 256) {
        int r = i >> 4, c = i & 15;
        size_t g = row0 + r;
        if (g >= N_NODES) g = N_NODES - 1;    // clamped read; stores guarded below
        uint4 v = ((const uint4*)(hp + g * DIM))[c];
        *(uint4*)&A[r][c * 8] = v;
    }
    __syncthreads();

    int w = t >> 6, l = t & 63;
    int arow = 16 * w + (l & 15);
    int kq = (l >> 4) * 8;
    int crow = 16 * w + (l >> 4) * 4;          // C-layout row base
    int ccol = l & 15;
    f16x8 af[4];
    f32x4 acc[8];

    // ---- GEMM1: A @ W1a + b1a, relu -> H ----
    #pragma unroll
    for (int kt = 0; kt < 4; ++kt) af[kt] = *(const f16x8*)&A[arow][kt * 32 + kq];
    #pragma unroll
    for (int nt = 0; nt < 8; ++nt) {
        float b = b1a[nt * 16 + ccol];
        acc[nt] = (f32x4){b, b, b, b};
    }
    #pragma unroll
    for (int nt = 0; nt < 8; ++nt)
        #pragma unroll
        for (int kt = 0; kt < 4; ++kt) {
            f16x8 bf = *(const f16x8*)(Pa + ((size_t)((kt << 3) + nt) * 64 + l) * 8);
            acc[nt] = __builtin_amdgcn_mfma_f32_16x16x32_f16(af[kt], bf, acc[nt], 0, 0, 0);
        }
    #pragma unroll
    for (int nt = 0; nt < 8; ++nt)
        #pragma unroll
        for (int r = 0; r < 4; ++r)
            H[crow + r][nt * 16 + ccol] = (_Float16)fmaxf(acc[nt][r], 0.f);
    __syncthreads();

    // ---- GEMM2: H @ W1b + b1b, relu -> A ----
    #pragma unroll
    for (int kt = 0; kt < 4; ++kt) af[kt] = *(const f16x8*)&H[arow][kt * 32 + kq];
    #pragma unroll
    for (int nt = 0; nt < 8; ++nt) {
        float b = b1b[nt * 16 + ccol];
        acc[nt] = (f32x4){b, b, b, b};
    }
    #pragma unroll
    for (int nt = 0; nt < 8; ++nt)
        #pragma unroll
        for (int kt = 0; kt < 4; ++kt) {
            f16x8 bf = *(const f16x8*)(Pb + ((size_t)((kt << 3) + nt) * 64 + l) * 8);
            acc[nt] = __builtin_amdgcn_mfma_f32_16x16x32_f16(af[kt], bf, acc[nt], 0, 0, 0);
        }
    #pragma unroll
    for (int nt = 0; nt < 8; ++nt)
        #pragma unroll
        for (int r = 0; r < 4; ++r)
            A[crow + r][nt * 16 + ccol] = (_Float16)fmaxf(acc[nt][r], 0.f);
    __syncthreads();

    // ---- GEMM3: x2 @ W2a (bias deferred past aggregation) -> y fp16 ----
    #pragma unroll
    for (int kt = 0; kt < 4; ++kt) af[kt] = *(const f16x8*)&A[arow][kt * 32 + kq];
    f32x4 ya[3];
    #pragma unroll
    for (int nt = 0; nt < 3; ++nt) ya[nt] = (f32x4){0.f, 0.f, 0.f, 0.f};
    #pragma unroll
    for (int nt = 0; nt < 3; ++nt)
        #pragma unroll
        for (int kt = 0; kt < 4; ++kt) {
            f16x8 bf = *(const f16x8*)(Pc + ((size_t)(kt * 3 + nt) * 64 + l) * 8);
            ya[nt] = __builtin_amdgcn_mfma_f32_16x16x32_f16(af[kt], bf, ya[nt], 0, 0, 0);
        }
    #pragma unroll
    for (int nt = 0; nt < 3; ++nt) {
        int col = nt * 16 + ccol;
        if (col < NC) {
            #pragma unroll
            for (int r = 0; r < 4; ++r) {
                size_t gr = row0 + crow + r;
                if (gr < N_NODES) y[gr * NC + col] = __float2half(ya[nt][r]);
            }
        }
    }
}

// ---------------- z = y + segsum(y[src]); h2 = relu(z+b2a); out = softmax(h2@W2b+b2b) ----------------
// Wide gather (12 edges / VMEM instr) + dual-buffer software pipeline + zero-row padding.
__device__ __forceinline__ void acc_row8(float* acc, uint4 v) {
    __half2 h;
    float2 f;
    *(unsigned*)&h = v.x; f = __half22float2(h); acc[0] += f.x; acc[1] += f.y;
    *(unsigned*)&h = v.y; f = __half22float2(h); acc[2] += f.x; acc[3] += f.y;
    *(unsigned*)&h = v.z; f = __half22float2(h); acc[4] += f.x; acc[5] += f.y;
    *(unsigned*)&h = v.w; f = __half22float2(h); acc[6] += f.x; acc[7] += f.y;
}

__global__ __launch_bounds__(256) void k_gather2(const __half* __restrict__ y, const int* __restrict__ row_ptr,
                                                 const int* __restrict__ csr_src, const float* __restrict__ b2a,
                                                 const float* __restrict__ W2b, const float* __restrict__ b2b,
                                                 float* __restrict__ out) {
    __shared__ float h2s[4][NC];
    int l = threadIdx.x & 63, wid = threadIdx.x >> 6;
    int n = blockIdx.x * 4 + wid;
    int g = l / 5, j = l - g * 5;            // g in 0..12 (lanes 60..63: g==12 -> zero row)
    const uint4* y4 = (const uint4*)y;

    float acc[8] = {0.f, 0.f, 0.f, 0.f, 0.f, 0.f, 0.f, 0.f};
    // self row via group 0 (issued first; independent of the loop chain)
    uint4 self;
    if (l < 5) self = y4[(size_t)n * 5 + j];

    int i0 = row_ptr[n], e = row_ptr[n + 1];
    int niter = (e - i0 + 11) / 12;
    uint4 cur;
    if (niter > 0) {
        int idx = i0 + g;
        int s = (g < 12 && idx < e) ? csr_src[idx] : N_NODES;
        cur = y4[(size_t)s * 5 + j];
    }
    for (int k = 1; k < niter; ++k) {
        int idx = i0 + k * 12 + g;
        int s = (g < 12 && idx < e) ? csr_src[idx] : N_NODES;
        uint4 nxt = y4[(size_t)s * 5 + j];    // issued before cur is consumed
        acc_row8(acc, cur);
        cur = nxt;
    }
    if (niter > 0) acc_row8(acc, cur);
    if (l < 5) acc_row8(acc, self);

    #pragma unroll
    for (int k = 0; k < 8; ++k) acc[k] += __shfl_down(acc[k], 30);   // g += 6
    #pragma unroll
    for (int k = 0; k < 8; ++k) acc[k] += __shfl_down(acc[k], 15);   // g += 3
    #pragma unroll
    for (int k = 0; k < 8; ++k) acc[k] += __shfl_down(acc[k], 5) + __shfl_down(acc[k], 10);

    if (l < 5) {
        float4 b0 = *(const float4*)(b2a + 8 * l);
        float4 b1 = *(const float4*)(b2a + 8 * l + 4);
        float4 h0, h1;
        h0.x = fmaxf(acc[0] + b0.x, 0.f); h0.y = fmaxf(acc[1] + b0.y, 0.f);
        h0.z = fmaxf(acc[2] + b0.z, 0.f); h0.w = fmaxf(acc[3] + b0.w, 0.f);
        h1.x = fmaxf(acc[4] + b1.x, 0.f); h1.y = fmaxf(acc[5] + b1.y, 0.f);
        h1.z = fmaxf(acc[6] + b1.z, 0.f); h1.w = fmaxf(acc[7] + b1.w, 0.f);
        *(float4*)&h2s[wid][8 * l] = h0;
        *(float4*)&h2s[wid][8 * l + 4] = h1;
    }
    __threadfence_block();   // same-wave LDS RAW only (each wave owns h2s[wid])

    float logit = -__builtin_inff();
    if (l < NC) {
        float a = b2b[l];
        #pragma unroll 4
        for (int k = 0; k < NC; ++k) a += h2s[wid][k] * W2b[k * NC + l];
        logit = a;
    }
    float m = logit;
    #pragma unroll
    for (int d = 32; d >= 1; d >>= 1) m = fmaxf(m, __shfl_xor(m, d, 64));
    float ev = (l < NC) ? __expf(logit - m) : 0.f;
    float s = ev;
    #pragma unroll
    for (int d = 32; d >= 1; d >>= 1) s += __shfl_xor(s, d, 64);
    if (l < NC) out[(size_t)n * NC + l] = ev / s;
}

extern "C" void kernel_launch(void* const* d_in, const int* in_sizes, int n_in,
                              void* d_out, int out_size, void* d_ws, size_t ws_size,
                              hipStream_t stream) {
    const float* x   = (const float*)d_in[0];
    const int2*  ei  = (const int2*)d_in[1];
    const float* W1a = (const float*)d_in[2];
    const float* b1a = (const float*)d_in[3];
    const float* W1b = (const float*)d_in[4];
    const float* b1b = (const float*)d_in[5];
    const float* W2a = (const float*)d_in[6];
    const float* b2a = (const float*)d_in[7];
    const float* W2b = (const float*)d_in[8];
    const float* b2b = (const float*)d_in[9];
    float* out = (float*)d_out;

    char* w = (char*)d_ws;
    int*    deg    = (int*)(w + 0);             // 100001 ints -> row_ptr after scan
    int*    bcur   = (int*)(w + 400128);        // 782 ints (bucket cursors, init by scan2)
    int*    bsums  = (int*)(w + 403328);        // 16 ints
    int*    csr    = (int*)(w + 403392);        // 1.6M ints (src grouped by dst)
    int*    stg    = (int*)(w + 6803392);       // 1.6M ints (packed, grouped by bucket)
    __half* xh     = (__half*)(w + 13203392);   // (100000+1)x128 fp16 (incl. zero row)
    __half* hp     = (__half*)(w + 38803648);   // 100000x128 fp16 (agg result)
    __half* y      = (__half*)(w + 64403648);   // (100000+1)x40 fp16 (incl. zero row)
    _Float16* Pa   = (_Float16*)(w + 72403776); // 32KB W1a frags
    _Float16* Pb   = (_Float16*)(w + 72436544); // 32KB W1b frags
    _Float16* Pc   = (_Float16*)(w + 72469312); // 12KB W2a frags (padded to 48 cols)
    // total ws needed: 72,481,600 bytes

    (void)hipMemsetAsync(w, 0, 400128, stream);  // zero deg only
    k_hist_cvt <<<N_EDGES / 256, 256, 0, stream>>>(ei, deg, x, xh, y);
    k_scan1    <<<SCAN_NB, SCAN_T, 0, stream>>>(deg, bsums);
    k_scan2    <<<SCAN_NB, SCAN_T, 0, stream>>>(deg, bsums, bcur);
    k_binfill  <<<NBLK_FILL, 256, 0, stream>>>(ei, bcur, stg);
    k_csr_local<<<NBUCKET, 256, 0, stream>>>(deg, stg, csr);
    k_pack     <<<19, 256, 0, stream>>>(W1a, W1b, W2a, Pa, Pb, Pc);
    k_gather1  <<<N_NODES / 4, 256, 0, stream>>>((const __half2*)xh, deg, csr, (__half2*)hp);
    k_mlp      <<<(N_NODES + 63) / 64, 256, 0, stream>>>(hp, Pa, Pb, Pc, b1a, b1b, y);
    k_gather2  <<<N_NODES / 4, 256, 0, stream>>>(y, deg, csr, b2a, W2b, b2b, out);
}

// Round 9
// 445.680 us; speedup vs baseline: 1.0380x; 1.0380x over previous
//
#include <hip/hip_runtime.h>
#include <hip/hip_fp16.h>

#define N_NODES 100000
#define N_EDGES 1600000
#define DIM 128
#define NC 40

#define BUCKET_SHIFT 7
#define BUCKET_NODES 128
#define NBUCKET ((N_NODES + BUCKET_NODES - 1) / BUCKET_NODES)   // 782
#define NBIN 1024                                               // padded bins for scan
#define EPB 4096                                                // edges per binfill block
#define NBLK_FILL ((N_EDGES + EPB - 1) / EPB)                   // 391

typedef _Float16 f16x8 __attribute__((ext_vector_type(8)));
typedef float f32x4 __attribute__((ext_vector_type(4)));

// ---------------- CSR hist + x -> fp16 convert + zero-row init (fused) ----------------
__global__ __launch_bounds__(256) void k_hist_cvt(const int2* __restrict__ ei, int* __restrict__ deg,
                                                  const float* __restrict__ x, __half* __restrict__ xh,
                                                  __half* __restrict__ y) {
    int i = blockIdx.x * 256 + threadIdx.x;       // 6250*256 == N_EDGES exactly
    if (blockIdx.x == 0) {
        // zero rows at index N_NODES (targets of branchless invalid-lane gathers)
        if (threadIdx.x < 16) ((uint4*)xh)[(size_t)N_NODES * (DIM / 8) + threadIdx.x] = (uint4){0, 0, 0, 0};
        else if (threadIdx.x < 21) ((uint4*)y)[(size_t)N_NODES * 5 + threadIdx.x - 16] = (uint4){0, 0, 0, 0};
    }
    int2 e = ei[i];
    atomicAdd(&deg[e.y + 1], 1);
    // convert 8 floats -> 8 halves; 6250*256*8 == N_NODES*DIM exactly
    float4 v0 = ((const float4*)x)[(size_t)i * 2];
    float4 v1 = ((const float4*)x)[(size_t)i * 2 + 1];
    __half2 h01 = __float22half2_rn(make_float2(v0.x, v0.y));
    __half2 h23 = __float22half2_rn(make_float2(v0.z, v0.w));
    __half2 h45 = __float22half2_rn(make_float2(v1.x, v1.y));
    __half2 h67 = __float22half2_rn(make_float2(v1.z, v1.w));
    uint4 o;
    o.x = *(unsigned*)&h01; o.y = *(unsigned*)&h23;
    o.z = *(unsigned*)&h45; o.w = *(unsigned*)&h67;
    ((uint4*)xh)[i] = o;
}

#define SCAN_N (N_NODES + 1)
#define SCAN_T 256
#define SCAN_PER 32
#define SCAN_CHUNK (SCAN_T * SCAN_PER)                      // 8192
#define SCAN_NB ((SCAN_N + SCAN_CHUNK - 1) / SCAN_CHUNK)    // 13

__global__ __launch_bounds__(SCAN_T) void k_scan1(int* __restrict__ a, int* __restrict__ bsums) {
    __shared__ int wtot[SCAN_T / 64];
    int t = threadIdx.x, lane = t & 63, wid = t >> 6;
    int base = blockIdx.x * SCAN_CHUNK + t * SCAN_PER;
    int v[SCAN_PER];
    int run = 0;
    #pragma unroll
    for (int j = 0; j < SCAN_PER; ++j) {
        int idx = base + j;
        int x = (idx < SCAN_N) ? a[idx] : 0;
        run += x;
        v[j] = run;
    }
    int incl = run;
    #pragma unroll
    for (int d = 1; d < 64; d <<= 1) {
        int u = __shfl_up(incl, d, 64);
        if (lane >= d) incl += u;
    }
    if (lane == 63) wtot[wid] = incl;
    __syncthreads();
    int add = incl - run;
    for (int w = 0; w < wid; ++w) add += wtot[w];
    #pragma unroll
    for (int j = 0; j < SCAN_PER; ++j) {
        int idx = base + j;
        if (idx < SCAN_N) a[idx] = v[j] + add;
    }
    if (t == 0) {
        int tot = 0;
        for (int w = 0; w < SCAN_T / 64; ++w) tot += wtot[w];
        bsums[blockIdx.x] = tot;
    }
}

// scan2 finalizes row_ptr and mirrors bucket bases into bcur (binfill's global cursors)
__global__ __launch_bounds__(SCAN_T) void k_scan2(int* __restrict__ a, const int* __restrict__ bsums,
                                                  int* __restrict__ bcur) {
    int off = 0;
    for (int i = 0; i < (int)blockIdx.x; ++i) off += bsums[i];
    int base = blockIdx.x * SCAN_CHUNK + threadIdx.x;
    #pragma unroll
    for (int j = 0; j < SCAN_PER; ++j) {
        int idx = base + j * SCAN_T;
        if (idx < SCAN_N) {
            int v = a[idx] + off;
            a[idx] = v;
            if ((idx & (BUCKET_NODES - 1)) == 0 && idx < N_NODES) bcur[idx >> BUCKET_SHIFT] = v;
        }
    }
}

// ---------------- binfill: LDS counting-sort edges by 128-node bucket, coalesced staged writes ----
// staged entry: src | (dst_local << 17)  (src<2^17, dst_local<2^7)
__global__ __launch_bounds__(256) void k_binfill(const int2* __restrict__ ei, int* __restrict__ bcur,
                                                 int* __restrict__ stg) {
    __shared__ int hist[NBIN];
    __shared__ int offs[NBIN];
    __shared__ int gbase[NBIN];
    __shared__ int cnt[NBIN];
    __shared__ int lds[EPB];
    __shared__ int wt[4];
    int t = threadIdx.x;
    int e0 = blockIdx.x * EPB;
    int bec = N_EDGES - e0; if (bec > EPB) bec = EPB;

    #pragma unroll
    for (int j = 0; j < NBIN / 256; ++j) { hist[t + j * 256] = 0; cnt[t + j * 256] = 0; }
    __syncthreads();

    // phase 1: histogram
    for (int k = 0; k < EPB / 256; ++k) {
        int i = e0 + t + k * 256;
        if (i < N_EDGES) {
            int2 e = ei[i];
            atomicAdd(&hist[e.y >> BUCKET_SHIFT], 1);
        }
    }
    __syncthreads();

    // phase 2: exclusive scan of hist[1024]
    int lane = t & 63, w = t >> 6;
    int h[4], p = 0;
    #pragma unroll
    for (int j = 0; j < 4; ++j) { h[j] = hist[t * 4 + j]; p += h[j]; }
    int inc = p;
    #pragma unroll
    for (int d = 1; d < 64; d <<= 1) {
        int u = __shfl_up(inc, d, 64);
        if (lane >= d) inc += u;
    }
    if (lane == 63) wt[w] = inc;
    __syncthreads();
    int add = inc - p;
    for (int k = 0; k < w; ++k) add += wt[k];
    int run = add;
    #pragma unroll
    for (int j = 0; j < 4; ++j) { offs[t * 4 + j] = run; run += h[j]; }
    __syncthreads();

    // phase 3: reserve global ranges (one atomic per non-empty bin)
    #pragma unroll
    for (int j = 0; j < 4; ++j) {
        int b = t * 4 + j;
        if (b < NBUCKET && h[j] > 0) gbase[b] = atomicAdd(&bcur[b], h[j]);
    }
    __syncthreads();

    // phase 4: scatter packed edges into LDS in bin order
    for (int k = 0; k < EPB / 256; ++k) {
        int i = e0 + t + k * 256;
        if (i < N_EDGES) {
            int2 e = ei[i];
            int b = e.y >> BUCKET_SHIFT;
            int pos = offs[b] + atomicAdd(&cnt[b], 1);
            lds[pos] = e.x | ((e.y & (BUCKET_NODES - 1)) << 17);
        }
    }
    __syncthreads();

    // phase 5: coalesced write-out (bin of position i via binary search on offs)
    for (int i = t; i < bec; i += 256) {
        int lo = 0, hi = NBIN - 1;
        while (lo < hi) { int mid = (lo + hi + 1) >> 1; if (offs[mid] <= i) lo = mid; else hi = mid - 1; }
        stg[gbase[lo] + (i - offs[lo])] = lds[i];
    }
}

// ---------------- per-bucket CSR fill: scatter confined to one block's 8KB window ----------------
__global__ __launch_bounds__(256) void k_csr_local(const int* __restrict__ row_ptr, const int* __restrict__ stg,
                                                   int* __restrict__ csr) {
    __shared__ int cur[BUCKET_NODES];
    int t = threadIdx.x, b = blockIdx.x;
    int n0 = b * BUCKET_NODES;
    int nn = N_NODES - n0; if (nn > BUCKET_NODES) nn = BUCKET_NODES;
    if (t < nn) cur[t] = row_ptr[n0 + t];
    __syncthreads();
    int beg = row_ptr[n0], end = row_ptr[n0 + nn];
    for (int i = beg + t; i < end; i += 256) {
        int e = stg[i];
        int dl = (e >> 17) & (BUCKET_NODES - 1);
        int pos = atomicAdd(&cur[dl], 1);
        csr[pos] = e & 0x1FFFF;
    }
}

// ---------------- pack W1a/W1b (128x128) and W2a (128x40->48) into fp16 MFMA B-frags ----------------
__global__ __launch_bounds__(256) void k_pack(const float* __restrict__ W1a, const float* __restrict__ W1b,
                                              const float* __restrict__ W2a,
                                              _Float16* __restrict__ Pa, _Float16* __restrict__ Pb,
                                              _Float16* __restrict__ Pc) {
    int bid = blockIdx.x, tid = threadIdx.x;
    if (bid < 16) {
        const float* W = (bid < 8) ? W1a : W1b;
        _Float16* P = (bid < 8) ? Pa : Pb;
        int t = (bid & 7) * 256 + tid;          // 0..2047
        int l = t & 63, nt = (t >> 6) & 7, kt = t >> 9;
        int n = nt * 16 + (l & 15);
        int kb = kt * 32 + (l >> 4) * 8;
        #pragma unroll
        for (int j = 0; j < 8; ++j)
            P[(size_t)t * 8 + j] = (_Float16)W[(size_t)(kb + j) * DIM + n];
    } else {
        int t = (bid - 16) * 256 + tid;         // 0..767
        if (t < 768) {
            int l = t & 63, u = t >> 6;          // u = kt*3 + nt
            int nt = u % 3, kt = u / 3;
            int n = nt * 16 + (l & 15);
            int kb = kt * 32 + (l >> 4) * 8;
            #pragma unroll
            for (int j = 0; j < 8; ++j) {
                float wv = (n < NC) ? W2a[(size_t)(kb + j) * NC + n] : 0.f;
                Pc[(size_t)t * 8 + j] = (_Float16)wv;
            }
        }
    }
}

// ---------------- layer 1 aggregation: hp = x + segsum(x[src]) ----------------
// Two rows per VMEM instruction: half-wave h (32 lanes x uint2 = 256 B) loads row s[2u+h].
// Per 8-row iteration: 4 x global_load_dwordx2 (512 B each). Cross-half combine via shfl_xor(32).
__global__ __launch_bounds__(256) void k_gather1(const __half* __restrict__ xh, const int* __restrict__ row_ptr,
                                                 const int* __restrict__ csr_src, __half* __restrict__ hp) {
    int l = threadIdx.x & 63, wid = threadIdx.x >> 6;
    int n = blockIdx.x * 4 + wid;
    int half = l >> 5, sub = l & 31;
    const uint2* x2 = (const uint2*)xh;            // row stride: 32 uint2

    // self row issued early (lanes 0..31 only; consumed after the loop)
    uint2 sv;
    if (half == 0) sv = x2[(size_t)n * 32 + sub];

    float4 acc = {0.f, 0.f, 0.f, 0.f};
    int i0 = row_ptr[n], e = row_ptr[n + 1];
    int niter = (e - i0 + 7) >> 3;
    for (int k = 0; k < niter; ++k) {
        int base = i0 + k * 8;
        int s[4];
        #pragma unroll
        for (int u = 0; u < 4; ++u) {
            int idx = base + u * 2 + half;
            s[u] = (idx < e) ? csr_src[idx] : N_NODES;   // N_NODES = zero row (L1-hot)
        }
        uint2 v[4];
        #pragma unroll
        for (int u = 0; u < 4; ++u) v[u] = x2[(size_t)s[u] * 32 + sub];
        #pragma unroll
        for (int u = 0; u < 4; ++u) {
            __half2 h0, h1;
            *(unsigned*)&h0 = v[u].x; *(unsigned*)&h1 = v[u].y;
            float2 f0 = __half22float2(h0), f1 = __half22float2(h1);
            acc.x += f0.x; acc.y += f0.y; acc.z += f1.x; acc.w += f1.y;
        }
    }
    // combine the two half-waves (lanes l and l^32 hold the same 4 dims)
    acc.x += __shfl_xor(acc.x, 32);
    acc.y += __shfl_xor(acc.y, 32);
    acc.z += __shfl_xor(acc.z, 32);
    acc.w += __shfl_xor(acc.w, 32);

    if (half == 0) {
        __half2 h0, h1;
        *(unsigned*)&h0 = sv.x; *(unsigned*)&h1 = sv.y;
        float2 f0 = __half22float2(h0), f1 = __half22float2(h1);
        acc.x += f0.x; acc.y += f0.y; acc.z += f1.x; acc.w += f1.y;
        __half2 o0 = __float22half2_rn(make_float2(acc.x, acc.y));
        __half2 o1 = __float22half2_rn(make_float2(acc.z, acc.w));
        uint2 ov;
        ov.x = *(unsigned*)&o0; ov.y = *(unsigned*)&o1;
        ((uint2*)hp)[(size_t)n * 32 + sub] = ov;
    }
}

// ---------------- fused MLP via fp16 MFMA: y = relu(relu(hp@W1a+b1a)@W1b+b1b) @ W2a ----------------
__global__ __launch_bounds__(256) void k_mlp(const __half* __restrict__ hp,
    const _Float16* __restrict__ Pa, const _Float16* __restrict__ Pb, const _Float16* __restrict__ Pc,
    const float* __restrict__ b1a, const float* __restrict__ b1b, __half* __restrict__ y) {
    __shared__ _Float16 A[64][136];   // +8 pad (16B): aligned frag reads
    __shared__ _Float16 H[64][136];
    int t = threadIdx.x;
    size_t row0 = (size_t)blockIdx.x * 64;

    for (int i = t; i < 1024; i += 256) {
        int r = i >> 4, c = i & 15;
        size_t g = row0 + r;
        if (g >= N_NODES) g = N_NODES - 1;    // clamped read; stores guarded below
        uint4 v = ((const uint4*)(hp + g * DIM))[c];
        *(uint4*)&A[r][c * 8] = v;
    }
    __syncthreads();

    int w = t >> 6, l = t & 63;
    int arow = 16 * w + (l & 15);
    int kq = (l >> 4) * 8;
    int crow = 16 * w + (l >> 4) * 4;          // C-layout row base
    int ccol = l & 15;
    f16x8 af[4];
    f32x4 acc[8];

    // ---- GEMM1: A @ W1a + b1a, relu -> H ----
    #pragma unroll
    for (int kt = 0; kt < 4; ++kt) af[kt] = *(const f16x8*)&A[arow][kt * 32 + kq];
    #pragma unroll
    for (int nt = 0; nt < 8; ++nt) {
        float b = b1a[nt * 16 + ccol];
        acc[nt] = (f32x4){b, b, b, b};
    }
    #pragma unroll
    for (int nt = 0; nt < 8; ++nt)
        #pragma unroll
        for (int kt = 0; kt < 4; ++kt) {
            f16x8 bf = *(const f16x8*)(Pa + ((size_t)((kt << 3) + nt) * 64 + l) * 8);
            acc[nt] = __builtin_amdgcn_mfma_f32_16x16x32_f16(af[kt], bf, acc[nt], 0, 0, 0);
        }
    #pragma unroll
    for (int nt = 0; nt < 8; ++nt)
        #pragma unroll
        for (int r = 0; r < 4; ++r)
            H[crow + r][nt * 16 + ccol] = (_Float16)fmaxf(acc[nt][r], 0.f);
    __syncthreads();

    // ---- GEMM2: H @ W1b + b1b, relu -> A ----
    #pragma unroll
    for (int kt = 0; kt < 4; ++kt) af[kt] = *(const f16x8*)&H[arow][kt * 32 + kq];
    #pragma unroll
    for (int nt = 0; nt < 8; ++nt) {
        float b = b1b[nt * 16 + ccol];
        acc[nt] = (f32x4){b, b, b, b};
    }
    #pragma unroll
    for (int nt = 0; nt < 8; ++nt)
        #pragma unroll
        for (int kt = 0; kt < 4; ++kt) {
            f16x8 bf = *(const f16x8*)(Pb + ((size_t)((kt << 3) + nt) * 64 + l) * 8);
            acc[nt] = __builtin_amdgcn_mfma_f32_16x16x32_f16(af[kt], bf, acc[nt], 0, 0, 0);
        }
    #pragma unroll
    for (int nt = 0; nt < 8; ++nt)
        #pragma unroll
        for (int r = 0; r < 4; ++r)
            A[crow + r][nt * 16 + ccol] = (_Float16)fmaxf(acc[nt][r], 0.f);
    __syncthreads();

    // ---- GEMM3: x2 @ W2a (bias deferred past aggregation) -> y fp16 ----
    #pragma unroll
    for (int kt = 0; kt < 4; ++kt) af[kt] = *(const f16x8*)&A[arow][kt * 32 + kq];
    f32x4 ya[3];
    #pragma unroll
    for (int nt = 0; nt < 3; ++nt) ya[nt] = (f32x4){0.f, 0.f, 0.f, 0.f};
    #pragma unroll
    for (int nt = 0; nt < 3; ++nt)
        #pragma unroll
        for (int kt = 0; kt < 4; ++kt) {
            f16x8 bf = *(const f16x8*)(Pc + ((size_t)(kt * 3 + nt) * 64 + l) * 8);
            ya[nt] = __builtin_amdgcn_mfma_f32_16x16x32_f16(af[kt], bf, ya[nt], 0, 0, 0);
        }
    #pragma unroll
    for (int nt = 0; nt < 3; ++nt) {
        int col = nt * 16 + ccol;
        if (col < NC) {
            #pragma unroll
            for (int r = 0; r < 4; ++r) {
                size_t gr = row0 + crow + r;
                if (gr < N_NODES) y[gr * NC + col] = __float2half(ya[nt][r]);
            }
        }
    }
}

// ---------------- z = y + segsum(y[src]); h2 = relu(z+b2a); out = softmax(h2@W2b+b2b) ----------------
// Wide gather (12 edges / VMEM instr) + dual-buffer software pipeline + zero-row padding.
__device__ __forceinline__ void acc_row8(float* acc, uint4 v) {
    __half2 h;
    float2 f;
    *(unsigned*)&h = v.x; f = __half22float2(h); acc[0] += f.x; acc[1] += f.y;
    *(unsigned*)&h = v.y; f = __half22float2(h); acc[2] += f.x; acc[3] += f.y;
    *(unsigned*)&h = v.z; f = __half22float2(h); acc[4] += f.x; acc[5] += f.y;
    *(unsigned*)&h = v.w; f = __half22float2(h); acc[6] += f.x; acc[7] += f.y;
}

__global__ __launch_bounds__(256) void k_gather2(const __half* __restrict__ y, const int* __restrict__ row_ptr,
                                                 const int* __restrict__ csr_src, const float* __restrict__ b2a,
                                                 const float* __restrict__ W2b, const float* __restrict__ b2b,
                                                 float* __restrict__ out) {
    __shared__ float h2s[4][NC];
    int l = threadIdx.x & 63, wid = threadIdx.x >> 6;
    int n = blockIdx.x * 4 + wid;
    int g = l / 5, j = l - g * 5;            // g in 0..12 (lanes 60..63: g==12 -> zero row)
    const uint4* y4 = (const uint4*)y;

    float acc[8] = {0.f, 0.f, 0.f, 0.f, 0.f, 0.f, 0.f, 0.f};
    // self row via group 0 (issued first; independent of the loop chain)
    uint4 self;
    if (l < 5) self = y4[(size_t)n * 5 + j];

    int i0 = row_ptr[n], e = row_ptr[n + 1];
    int niter = (e - i0 + 11) / 12;
    uint4 cur;
    if (niter > 0) {
        int idx = i0 + g;
        int s = (g < 12 && idx < e) ? csr_src[idx] : N_NODES;
        cur = y4[(size_t)s * 5 + j];
    }
    for (int k = 1; k < niter; ++k) {
        int idx = i0 + k * 12 + g;
        int s = (g < 12 && idx < e) ? csr_src[idx] : N_NODES;
        uint4 nxt = y4[(size_t)s * 5 + j];    // issued before cur is consumed
        acc_row8(acc, cur);
        cur = nxt;
    }
    if (niter > 0) acc_row8(acc, cur);
    if (l < 5) acc_row8(acc, self);

    #pragma unroll
    for (int k = 0; k < 8; ++k) acc[k] += __shfl_down(acc[k], 30);   // g += 6
    #pragma unroll
    for (int k = 0; k < 8; ++k) acc[k] += __shfl_down(acc[k], 15);   // g += 3
    #pragma unroll
    for (int k = 0; k < 8; ++k) acc[k] += __shfl_down(acc[k], 5) + __shfl_down(acc[k], 10);

    if (l < 5) {
        float4 b0 = *(const float4*)(b2a + 8 * l);
        float4 b1 = *(const float4*)(b2a + 8 * l + 4);
        float4 h0, h1;
        h0.x = fmaxf(acc[0] + b0.x, 0.f); h0.y = fmaxf(acc[1] + b0.y, 0.f);
        h0.z = fmaxf(acc[2] + b0.z, 0.f); h0.w = fmaxf(acc[3] + b0.w, 0.f);
        h1.x = fmaxf(acc[4] + b1.x, 0.f); h1.y = fmaxf(acc[5] + b1.y, 0.f);
        h1.z = fmaxf(acc[6] + b1.z, 0.f); h1.w = fmaxf(acc[7] + b1.w, 0.f);
        *(float4*)&h2s[wid][8 * l] = h0;
        *(float4*)&h2s[wid][8 * l + 4] = h1;
    }
    __threadfence_block();   // same-wave LDS RAW only (each wave owns h2s[wid])

    float logit = -__builtin_inff();
    if (l < NC) {
        float a = b2b[l];
        #pragma unroll 4
        for (int k = 0; k < NC; ++k) a += h2s[wid][k] * W2b[k * NC + l];
        logit = a;
    }
    float m = logit;
    #pragma unroll
    for (int d = 32; d >= 1; d >>= 1) m = fmaxf(m, __shfl_xor(m, d, 64));
    float ev = (l < NC) ? __expf(logit - m) : 0.f;
    float s = ev;
    #pragma unroll
    for (int d = 32; d >= 1; d >>= 1) s += __shfl_xor(s, d, 64);
    if (l < NC) out[(size_t)n * NC + l] = ev / s;
}

extern "C" void kernel_launch(void* const* d_in, const int* in_sizes, int n_in,
                              void* d_out, int out_size, void* d_ws, size_t ws_size,
                              hipStream_t stream) {
    const float* x   = (const float*)d_in[0];
    const int2*  ei  = (const int2*)d_in[1];
    const float* W1a = (const float*)d_in[2];
    const float* b1a = (const float*)d_in[3];
    const float* W1b = (const float*)d_in[4];
    const float* b1b = (const float*)d_in[5];
    const float* W2a = (const float*)d_in[6];
    const float* b2a = (const float*)d_in[7];
    const float* W2b = (const float*)d_in[8];
    const float* b2b = (const float*)d_in[9];
    float* out = (float*)d_out;

    char* w = (char*)d_ws;
    int*    deg    = (int*)(w + 0);             // 100001 ints -> row_ptr after scan
    int*    bcur   = (int*)(w + 400128);        // 782 ints (bucket cursors, init by scan2)
    int*    bsums  = (int*)(w + 403328);        // 16 ints
    int*    csr    = (int*)(w + 403392);        // 1.6M ints (src grouped by dst)
    int*    stg    = (int*)(w + 6803392);       // 1.6M ints (packed, grouped by bucket)
    __half* xh     = (__half*)(w + 13203392);   // (100000+1)x128 fp16 (incl. zero row)
    __half* hp     = (__half*)(w + 38803648);   // 100000x128 fp16 (agg result)
    __half* y      = (__half*)(w + 64403648);   // (100000+1)x40 fp16 (incl. zero row)
    _Float16* Pa   = (_Float16*)(w + 72403776); // 32KB W1a frags
    _Float16* Pb   = (_Float16*)(w + 72436544); // 32KB W1b frags
    _Float16* Pc   = (_Float16*)(w + 72469312); // 12KB W2a frags (padded to 48 cols)
    // total ws needed: 72,481,600 bytes

    (void)hipMemsetAsync(w, 0, 400128, stream);  // zero deg only
    k_hist_cvt <<<N_EDGES / 256, 256, 0, stream>>>(ei, deg, x, xh, y);
    k_scan1    <<<SCAN_NB, SCAN_T, 0, stream>>>(deg, bsums);
    k_scan2    <<<SCAN_NB, SCAN_T, 0, stream>>>(deg, bsums, bcur);
    k_binfill  <<<NBLK_FILL, 256, 0, stream>>>(ei, bcur, stg);
    k_csr_local<<<NBUCKET, 256, 0, stream>>>(deg, stg, csr);
    k_pack     <<<19, 256, 0, stream>>>(W1a, W1b, W2a, Pa, Pb, Pc);
    k_gather1  <<<N_NODES / 4, 256, 0, stream>>>(xh, deg, csr, hp);
    k_mlp      <<<(N_NODES + 63) / 64, 256, 0, stream>>>(hp, Pa, Pb, Pc, b1a, b1b, y);
    k_gather2  <<<N_NODES / 4, 256, 0, stream>>>(y, deg, csr, b2a, W2b, b2b, out);
}